// Round 2
// baseline (400.225 us; speedup 1.0000x reference)
//
#include <hip/hip_runtime.h>
#include <stdint.h>

#define NB 8192
#define TSTEPS 1024
#define OUT_TSTRIDE (8 * NB)   // floats per time step in out[T,8,B]
#define TILE 32                // time steps per phase-1 LDS tile
#define LDS_F 6144             // 3 arrays * 32 rows * 64 basins

// ---------------------------------------------------------------------------
// Checkpoint two-phase scheme.
//
// Phase 1: one wave per 64-basin group (128 blocks x 64 threads) runs the
//   full 1024-step state recurrence ONCE, double-buffering forcings through
//   LDS with global_load_lds (deep prefetch without VGPR cost), and stores
//   (snow, soil) checkpoints every SEGLEN steps into d_ws.  Serial-latency
//   bound (~40 cyc/step chain), loads hidden: ~17-25 us.
//
// Phase 2: wave = (basin-group, segment).  128 groups x (1024/SEGLEN)
//   segments; each wave restarts from its checkpoint and computes+stores its
//   SEGLEN steps for all 8 channels.  Forcings read exactly once device-wide,
//   outputs written once: pure streaming, no LDS, no barriers -> HBM-bound
//   (~356 MB ~ 57 us at 6.3 TB/s).
//
// Per-step arithmetic is kept identical to the previously-validated kernel
// (absmax 0.125) — the phase split changes scheduling, not math.
// ---------------------------------------------------------------------------

__device__ __forceinline__ float sigmoidf_(float x) {
    return 1.0f / (1.0f + __expf(-x));
}

__device__ __forceinline__ void async16(const float* g, float* l) {
    __builtin_amdgcn_global_load_lds(
        (const __attribute__((address_space(1))) void*)g,
        (__attribute__((address_space(3))) void*)l, 16, 0, 0);
}

struct Params {
    float f, Smax, Qmax, Df, Tmax, Tmin, rSmax, nf;
};

__device__ __forceinline__ Params load_params(const float* __restrict__ spn,
                                              int basin) {
    const float* p6 = spn + (size_t)basin * 6;
    Params p;
    p.f     = 0.1f * sigmoidf_(p6[0]);
    p.Smax  = 100.0f + 1400.0f * sigmoidf_(p6[1]);
    p.Qmax  = 10.0f + 40.0f * sigmoidf_(p6[2]);
    p.Df    = 5.0f * sigmoidf_(p6[3]);
    p.Tmax  = 3.0f * sigmoidf_(p6[4]);
    p.Tmin  = -3.0f + 3.0f * sigmoidf_(p6[5]);
    p.rSmax = 1.0f / p.Smax;
    p.nf    = -p.f;
    return p;
}

struct Flux {
    float snowfall, rainfall, melt, evap, baseflow, surfaceflow, d_snow, d_soil;
};

// One EXP-HYDRO step; identical op order to the validated kernel.
__device__ __forceinline__ Flux hydro_step(const Params& p, float& snow,
                                           float& soil, float P, float Tm,
                                           float Pe) {
    Flux o;
    o.snowfall    = (Tm < p.Tmin) ? P : 0.0f;
    o.rainfall    = P - o.snowfall;
    o.melt        = fminf(snow, p.Df * fmaxf(Tm - p.Tmax, 0.0f));
    o.evap        = Pe * fminf(soil * p.rSmax, 1.0f);
    o.baseflow    = p.Qmax * __expf(p.nf * fmaxf(p.Smax - soil, 0.0f));
    o.surfaceflow = fmaxf(soil - p.Smax, 0.0f);
    o.d_snow      = o.snowfall - o.melt;
    o.d_soil = (((o.rainfall + o.melt) - o.evap) - o.baseflow) - o.surfaceflow;
    snow = fmaxf(snow + o.d_snow, 1e-6f);
    soil = fmaxf(soil + o.d_soil, 1e-6f);
    return o;
}

// Stage 3 arrays x TILE(32) rows x 64 basins into LDS (SoA [arr][row][64]),
// async, 16B/lane, 24 calls per 64-lane wave (24 KB per tile).
// LDS dest per call = wave-uniform base + lane*16 (hardware requirement).
__device__ __forceinline__ void fill64(const float* __restrict__ prcp,
                                       const float* __restrict__ temp,
                                       const float* __restrict__ pet,
                                       float* lds, int t0, int lane,
                                       int gbase) {
#pragma unroll
    for (int k = 0; k < 24; ++k) {
        const float* src = (k < 8) ? prcp : ((k < 16) ? temp : pet);
        int row = ((k & 7) << 2) + (lane >> 4);  // 0..31 within tile
        int t   = t0 + row;
        t       = (t > TSTEPS - 1) ? (TSTEPS - 1) : t;  // clamp tail prefetch
        const float* g = src + (size_t)t * NB + gbase + ((lane & 15) << 2);
        float* l       = lds + (k << 8) + (lane << 2);
        async16(g, l);
    }
}

// Phase 1: 128 blocks x 64 threads; block = one basin-group.  Runs the full
// recurrence once, writing checkpoints (state BEFORE step t, t % SEGLEN == 0).
template <int SEGLEN>
__global__ void __launch_bounds__(64)
hydro_phase1(const float* __restrict__ prcp, const float* __restrict__ temp,
             const float* __restrict__ pet, const float* __restrict__ spn,
             float* __restrict__ ckpt) {
    __shared__ float lds[2][LDS_F];  // 48 KB double buffer
    const int lane  = threadIdx.x;   // 0..63
    const int g     = blockIdx.x;    // 0..127
    const int gbase = g * 64;
    const int basin = gbase + lane;

    const Params prm = load_params(spn, basin);
    float snow = 0.0f, soil = 0.0f;

    fill64(prcp, temp, pet, lds[0], 0, lane, gbase);
    __syncthreads();  // drains async fill (implicit vmcnt(0) before barrier)

    for (int tile = 0; tile < TSTEPS / TILE; ++tile) {
        const int cur = tile & 1;
        // prefetch next tile; drained by the barrier BELOW (a full tile of
        // compute in between -> ~900cy HBM latency fully hidden)
        fill64(prcp, temp, pet, lds[cur ^ 1], (tile + 1) * TILE, lane, gbase);

        const float* lp = lds[cur];
#pragma unroll 16
        for (int i = 0; i < TILE; ++i) {
            const int t = tile * TILE + i;
            if ((t & (SEGLEN - 1)) == 0) {
                const int s = t / SEGLEN;
                ckpt[(size_t)(2 * s) * NB + basin]     = snow;
                ckpt[(size_t)(2 * s + 1) * NB + basin] = soil;
            }
            const float P  = lp[i * 64 + lane];          // 2-way bank: free
            const float Tm = lp[2048 + i * 64 + lane];
            const float Pe = lp[4096 + i * 64 + lane];
            (void)hydro_step(prm, snow, soil, P, Tm, Pe);  // fluxes DCE'd
        }
        __syncthreads();
    }
}

// Phase 2: wave = (group g, segment s).  wid = s*128 + g, so a block's 4
// waves are 4 adjacent groups at the SAME segment -> contiguous loads/stores,
// and all blocks of a group land on the same XCD (stride 128 == 0 mod 8).
template <int SEGLEN>
__global__ void __launch_bounds__(256, 4)
hydro_phase2(const float* __restrict__ prcp, const float* __restrict__ temp,
             const float* __restrict__ pet, const float* __restrict__ spn,
             const float* __restrict__ ckpt, float* __restrict__ out) {
    const int tid   = threadIdx.x;
    const int lane  = tid & 63;
    const int wid   = (blockIdx.x << 2) + (tid >> 6);
    const int g     = wid & 127;
    const int s     = wid >> 7;
    const int basin = g * 64 + lane;

    const Params prm = load_params(spn, basin);

    float snow, soil;
    if (SEGLEN == 1024) {  // no-workspace fallback: single segment from zero
        snow = 0.0f;
        soil = 0.0f;
    } else {
        snow = ckpt[(size_t)(2 * s) * NB + basin];
        soil = ckpt[(size_t)(2 * s + 1) * NB + basin];
    }

    const int t0 = s * SEGLEN;
#pragma unroll 8
    for (int i = 0; i < SEGLEN; ++i) {
        const int t     = t0 + i;
        const size_t fo = (size_t)t * NB + basin;
        const float P   = prcp[fo];
        const float Tm  = temp[fo];
        const float Pe  = pet[fo];

        const Flux fl = hydro_step(prm, snow, soil, P, Tm, Pe);

        float* o = out + (size_t)t * OUT_TSTRIDE + basin;
        o[0 * NB] = fl.snowfall;   // each store: 64 lanes x 4B contiguous
        o[1 * NB] = fl.rainfall;
        o[2 * NB] = fl.melt;
        o[3 * NB] = fl.evap;
        o[4 * NB] = fl.baseflow;
        o[5 * NB] = fl.surfaceflow;
        o[6 * NB] = fl.d_snow;
        o[7 * NB] = fl.d_soil;
    }
}

extern "C" void kernel_launch(void* const* d_in, const int* in_sizes, int n_in,
                              void* d_out, int out_size, void* d_ws,
                              size_t ws_size, hipStream_t stream) {
    const float* prcp = (const float*)d_in[0];
    const float* temp = (const float*)d_in[1];
    const float* pet  = (const float*)d_in[2];
    const float* spn  = (const float*)d_in[3];
    float* out        = (float*)d_out;
    float* ckpt       = (float*)d_ws;

    const size_t need32  = (size_t)(TSTEPS / 32) * 2 * NB * sizeof(float);  // 2 MB
    const size_t need128 = (size_t)(TSTEPS / 128) * 2 * NB * sizeof(float); // 512 KB

    if (ws_size >= need32) {
        // 32 segments: phase2 = 128*32 = 4096 waves (16/CU resident)
        hydro_phase1<32><<<dim3(128), dim3(64), 0, stream>>>(prcp, temp, pet,
                                                             spn, ckpt);
        hydro_phase2<32><<<dim3(1024), dim3(256), 0, stream>>>(
            prcp, temp, pet, spn, ckpt, out);
    } else if (ws_size >= need128) {
        hydro_phase1<128><<<dim3(128), dim3(64), 0, stream>>>(prcp, temp, pet,
                                                              spn, ckpt);
        hydro_phase2<128><<<dim3(256), dim3(256), 0, stream>>>(
            prcp, temp, pet, spn, ckpt, out);
    } else {
        // no usable workspace: serial-per-basin fallback (slow but correct)
        hydro_phase2<1024><<<dim3(32), dim3(256), 0, stream>>>(
            prcp, temp, pet, spn, nullptr, out);
    }
}

// Round 3
// 384.986 us; speedup vs baseline: 1.0396x; 1.0396x over previous
//
#include <hip/hip_runtime.h>
#include <stdint.h>

#define NB 8192
#define TSTEPS 1024
#define OUT_TSTRIDE (8 * NB)   // floats per time step in out[T,8,B]
#define TILE 32                // steps per segment / LDS tile
#define NSEG (TSTEPS / TILE)   // 32 segments
#define NBUF 4                 // forcing ring slots
#define TILE_F (3 * TILE * 64) // 6144 floats per slot (prcp|temp|pet)
#define HALF 16                // consumer steps per round

// ---------------------------------------------------------------------------
// Fused producer-consumer scan split: ONE dispatch, NO workspace.
//
// Block = one 64-basin group (128 blocks x 192 thr).  Wave 0 (producer) runs
// the serial 1024-step recurrence once, staging forcings global->LDS ring
// (global_load_lds, 4 slots) and publishing (snow,soil) checkpoints per
// 32-step segment into an LDS ring.  Waves 1-2 (consumers) replay segments
// from checkpoints one round behind, 16 steps/round (2-round window), and
// store all 8 flux channels.  One __syncthreads per round; in round r the
// live ring slots {r, r+1, r-1, r-2} mod 4 are distinct -> race-free.
//
// Forcings read ONCE (shared LDS), outputs written once: 352 MB ~ 57 us
// BW-bound; the producer's ~17 us serial chain hides under the streaming.
// Per-step math identical to the validated kernels (absmax 0.125).
// ---------------------------------------------------------------------------

__device__ __forceinline__ float sigmoidf_(float x) {
    return 1.0f / (1.0f + __expf(-x));
}

__device__ __forceinline__ void async16(const float* g, float* l) {
    __builtin_amdgcn_global_load_lds(
        (const __attribute__((address_space(1))) void*)g,
        (__attribute__((address_space(3))) void*)l, 16, 0, 0);
}

struct Params {
    float f, Smax, Qmax, Df, Tmax, Tmin, rSmax, nf;
};

__device__ __forceinline__ Params load_params(const float* __restrict__ spn,
                                              int basin) {
    const float* p6 = spn + (size_t)basin * 6;
    Params p;
    p.f     = 0.1f * sigmoidf_(p6[0]);
    p.Smax  = 100.0f + 1400.0f * sigmoidf_(p6[1]);
    p.Qmax  = 10.0f + 40.0f * sigmoidf_(p6[2]);
    p.Df    = 5.0f * sigmoidf_(p6[3]);
    p.Tmax  = 3.0f * sigmoidf_(p6[4]);
    p.Tmin  = -3.0f + 3.0f * sigmoidf_(p6[5]);
    p.rSmax = 1.0f / p.Smax;
    p.nf    = -p.f;
    return p;
}

struct Flux {
    float snowfall, rainfall, melt, evap, baseflow, surfaceflow, d_snow, d_soil;
};

// One EXP-HYDRO step; identical op order to the validated kernels.
__device__ __forceinline__ Flux hydro_step(const Params& p, float& snow,
                                           float& soil, float P, float Tm,
                                           float Pe) {
    Flux o;
    o.snowfall    = (Tm < p.Tmin) ? P : 0.0f;
    o.rainfall    = P - o.snowfall;
    o.melt        = fminf(snow, p.Df * fmaxf(Tm - p.Tmax, 0.0f));
    o.evap        = Pe * fminf(soil * p.rSmax, 1.0f);
    o.baseflow    = p.Qmax * __expf(p.nf * fmaxf(p.Smax - soil, 0.0f));
    o.surfaceflow = fmaxf(soil - p.Smax, 0.0f);
    o.d_snow      = o.snowfall - o.melt;
    o.d_soil = (((o.rainfall + o.melt) - o.evap) - o.baseflow) - o.surfaceflow;
    snow = fmaxf(snow + o.d_snow, 1e-6f);
    soil = fmaxf(soil + o.d_soil, 1e-6f);
    return o;
}

// Stage 3 arrays x 32 rows x 64 basins into one ring slot (SoA [arr][row][64]),
// async, 16B/lane, 24 calls by the producer wave (24 KB per tile).
// LDS dest per call = wave-uniform base + lane*16 (hardware requirement).
// (Identical mapping to the round-2-verified fill64.)
__device__ __forceinline__ void fill64(const float* __restrict__ prcp,
                                       const float* __restrict__ temp,
                                       const float* __restrict__ pet,
                                       float* lds, int t0, int lane,
                                       int gbase) {
#pragma unroll
    for (int k = 0; k < 24; ++k) {
        const float* src = (k < 8) ? prcp : ((k < 16) ? temp : pet);
        int row = ((k & 7) << 2) + (lane >> 4);  // 0..31 within tile
        int t   = t0 + row;
        t       = (t > TSTEPS - 1) ? (TSTEPS - 1) : t;  // clamp tail
        const float* g = src + (size_t)t * NB + gbase + ((lane & 15) << 2);
        float* l       = lds + (k << 8) + (lane << 2);
        async16(g, l);
    }
}

extern "C" __global__ void __launch_bounds__(192, 1)
hydro_fused(const float* __restrict__ prcp, const float* __restrict__ temp,
            const float* __restrict__ pet, const float* __restrict__ spn,
            float* __restrict__ out) {
    __shared__ float fbuf[NBUF][TILE_F];   // 96 KB forcing ring
    __shared__ float ckpt[4][2][64];       // 2 KB checkpoint ring

    const int tid   = threadIdx.x;
    const int lane  = tid & 63;
    const int w     = tid >> 6;            // 0 producer, 1..2 consumers
    const int g     = blockIdx.x;          // 0..127 basin-group
    const int gbase = g * 64;
    const int basin = gbase + lane;

    const Params prm = load_params(spn, basin);

    float psnow = 0.0f, psoil = 0.0f;      // producer state (w0)
    float csnow = 0.0f, csoil = 0.0f;      // consumer state (w1/w2)

    if (w == 0) fill64(prcp, temp, pet, fbuf[0], 0, lane, gbase);
    __syncthreads();  // drains prologue fill (implicit vmcnt(0))

    for (int r = 0; r < NSEG + 2; ++r) {   // rounds 0..33
        if (w == 0) {
            if (r < NSEG) {
                // publish checkpoint: state BEFORE segment r
                ckpt[r & 3][0][lane] = psnow;
                ckpt[r & 3][1][lane] = psoil;
                // prefetch tile r+1 (slot (r+1)&3 is dead: held tile r-3,
                // whose consumer window ended in round r-1)
                if (r + 1 < NSEG)
                    fill64(prcp, temp, pet, fbuf[(r + 1) & 3],
                           (r + 1) * TILE, lane, gbase);
                // advance the recurrence through segment r
                const float* lp = fbuf[r & 3];
#pragma unroll 8
                for (int i = 0; i < TILE; ++i) {
                    const float P  = lp[i * 64 + lane];
                    const float Tm = lp[2048 + i * 64 + lane];
                    const float Pe = lp[4096 + i * 64 + lane];
                    (void)hydro_step(prm, psnow, psoil, P, Tm, Pe);
                }
            }
        } else {
            // consumer c handles segments of parity c; segment s spans
            // rounds s+1 (steps 0..15, from ckpt) and s+2 (steps 16..31).
            const int c = w - 1;
            int s, phase;
            if (((r - 1) & 1) == c) { s = r - 1; phase = 0; }
            else                    { s = r - 2; phase = 1; }
            if (s >= 0 && s < NSEG) {
                if (phase == 0) {
                    csnow = ckpt[s & 3][0][lane];
                    csoil = ckpt[s & 3][1][lane];
                }
                const float* lp = fbuf[s & 3];
                float* o = out +
                           (size_t)(s * TILE + phase * HALF) * OUT_TSTRIDE +
                           gbase + lane;
#pragma unroll 4
                for (int i = 0; i < HALF; ++i) {
                    const int row  = phase * HALF + i;
                    const float P  = lp[row * 64 + lane];
                    const float Tm = lp[2048 + row * 64 + lane];
                    const float Pe = lp[4096 + row * 64 + lane];

                    const Flux fl = hydro_step(prm, csnow, csoil, P, Tm, Pe);

                    o[0 * NB] = fl.snowfall;  // 64 lanes x 4B contiguous
                    o[1 * NB] = fl.rainfall;
                    o[2 * NB] = fl.melt;
                    o[3 * NB] = fl.evap;
                    o[4 * NB] = fl.baseflow;
                    o[5 * NB] = fl.surfaceflow;
                    o[6 * NB] = fl.d_snow;
                    o[7 * NB] = fl.d_soil;
                    o += OUT_TSTRIDE;
                }
            }
        }
        // end of round: drains fills (ready for producer next round) and
        // consumer stores; publishes ckpt + forcing slots across waves
        __syncthreads();
    }
}

extern "C" void kernel_launch(void* const* d_in, const int* in_sizes, int n_in,
                              void* d_out, int out_size, void* d_ws,
                              size_t ws_size, hipStream_t stream) {
    const float* prcp = (const float*)d_in[0];
    const float* temp = (const float*)d_in[1];
    const float* pet  = (const float*)d_in[2];
    const float* spn  = (const float*)d_in[3];
    float* out        = (float*)d_out;

    // ONE dispatch, no workspace use (avoids ws re-poison + extra launch).
    hydro_fused<<<dim3(128), dim3(192), 0, stream>>>(prcp, temp, pet, spn,
                                                     out);
}

// Round 5
// 367.786 us; speedup vs baseline: 1.0882x; 1.0468x over previous
//
#include <hip/hip_runtime.h>
#include <stdint.h>

#define NB 8192
#define OUT_TSTRIDE (8 * NB)   // floats per time step in out[T,8,B]
#define TILE 32                // time steps per LDS tile
#define LDS_F 6144             // 3 arrays * 32 rows * 64 basins

__device__ __forceinline__ float sigmoidf_(float x) {
    return 1.0f / (1.0f + __expf(-x));
}

__device__ __forceinline__ void async16(const float* g, float* l) {
    __builtin_amdgcn_global_load_lds(
        (const __attribute__((address_space(1))) void*)g,
        (__attribute__((address_space(3))) void*)l, 16, 0, 0);
}

// Stage 3 arrays x TILE rows x 64 basins into lds (SoA: [arr][row][basin]),
// async, 16B per lane per call, 6 calls per thread (256 threads * 6 * 16B = 24KB).
// LDS dest per wave = wave-uniform base + lane*16 (hardware requirement).
__device__ __forceinline__ void fill_tile(const float* __restrict__ prcp,
                                          const float* __restrict__ temp,
                                          const float* __restrict__ pet,
                                          float* lds, int t0, int tid,
                                          int gbase) {
#pragma unroll
    for (int r = 0; r < 6; ++r) {
        const float* src = (r < 2) ? prcp : ((r < 4) ? temp : pet);
        int tt = ((r & 1) << 4) + (tid >> 4);   // row 0..31 within tile
        int t  = t0 + tt;
        t      = (t > 1023) ? 1023 : t;          // clamp tail prefetch
        const float* g = src + (size_t)t * NB + gbase + ((tid & 15) << 2);
        float* l       = lds + (r << 10) + (tid << 2);
        async16(g, l);
    }
}

// One wave: channel pair CP for 64 basins; compute tiles [0, ntiles),
// store the pair when tile in [lo1,hi1).
template <int CP>
__device__ void run(const float* __restrict__ prcp,
                    const float* __restrict__ temp,
                    const float* __restrict__ pet, float* __restrict__ out,
                    float (*lds)[LDS_F], int tid, int lane, int gbase,
                    int basin, int ntiles, int lo1, int hi1,
                    float f, float Smax, float Qmax, float Df, float Tmax,
                    float Tmin) {
    const float rSmax = 1.0f / Smax;
    const float nf    = -f;
    float snow = 0.0f, soil = 0.0f;
    float* const outBase = out + (size_t)(2 * CP) * NB + basin;

    fill_tile(prcp, temp, pet, lds[0], 0, tid, gbase);
    __syncthreads();   // drains the async fill (implicit vmcnt(0) before barrier)

    for (int tile = 0; tile < ntiles; ++tile) {
        const int cur = tile & 1;
        // async prefetch next tile into the other buffer; drained by the
        // barrier BELOW (full tile of compute in between -> latency hidden)
        fill_tile(prcp, temp, pet, lds[cur ^ 1], (tile + 1) * TILE, tid, gbase);

        const bool doStore = (tile >= lo1 && tile < hi1);
        const float* lp = lds[cur];
        float* o        = outBase + (size_t)tile * TILE * OUT_TSTRIDE;
#pragma unroll
        for (int i = 0; i < TILE; ++i) {
            const float P  = lp[i * 64 + lane];          // bank = lane%32: free
            const float Tm = lp[2048 + i * 64 + lane];
            const float Pe = lp[4096 + i * 64 + lane];

            const float snowfall    = (Tm < Tmin) ? P : 0.0f;
            const float rainfall    = P - snowfall;
            const float melt        = fminf(snow, Df * fmaxf(Tm - Tmax, 0.0f));
            const float evap        = Pe * fminf(soil * rSmax, 1.0f);
            const float baseflow    = Qmax * __expf(nf * fmaxf(Smax - soil, 0.0f));
            const float surfaceflow = fmaxf(soil - Smax, 0.0f);
            const float d_snow      = snowfall - melt;
            const float d_soil =
                (((rainfall + melt) - evap) - baseflow) - surfaceflow;
            snow = fmaxf(snow + d_snow, 1e-6f);
            soil = fmaxf(soil + d_soil, 1e-6f);

            if (doStore) {   // wave-uniform -> scalar branch
                float sv0, sv1;
                if (CP == 0)      { sv0 = snowfall; sv1 = rainfall; }
                else if (CP == 1) { sv0 = melt;     sv1 = evap; }
                else if (CP == 2) { sv0 = baseflow; sv1 = surfaceflow; }
                else              { sv0 = d_snow;   sv1 = d_soil; }
                o[(size_t)i * OUT_TSTRIDE]      = sv0;
                o[(size_t)i * OUT_TSTRIDE + NB] = sv1;
            }
        }
        __syncthreads();   // compute done + next fill drained; swap buffers
    }
}

// Grid: 512 blocks = 128 basin-groups x 4 time-types, 2 blocks/CU.
//   CONTIGUOUS segment pairing: type t stores segments {2t, 2t+1} (tiles
//   [8t, 8t+8)) and therefore only computes the prefix [0, 8t+8).  Total
//   recompute = 8+16+24+32 = 80 tiles/group vs 104 for the old {t, 7-t}
//   pairing (-23% VALU issue); stored values identical (every type replays
//   the same deterministic prefix).  Dispatch pairing: blocks b and b+256
//   share the slot (likely same CU) and carry complementary types {0,3} or
//   {1,2} -> 40 tiles per slot either way: balanced.
//   All 4 type-blocks of a group share blockIdx%8 -> same XCD -> the 3.25x
//   forcing re-read dedups in L2/L3 (96 MB forcings fit the 256 MB L3, so
//   HBM read traffic stays ~1x).
// Block: 256 threads = 4 waves; wave w = channel pair {2w, 2w+1}.
extern "C" __global__ void __launch_bounds__(256, 2)
    hydro_kernel(const float* __restrict__ prcp, const float* __restrict__ temp,
                 const float* __restrict__ pet, const float* __restrict__ spn,
                 float* __restrict__ out) {
    __shared__ float lds[2][LDS_F];   // 48 KB double buffer (2 blocks/CU = 96 KB)

    const int tid  = threadIdx.x;
    const int lane = tid & 63;
    const int w    = tid >> 6;
    const int b    = blockIdx.x;
    const int idx  = b & 255;
    const int pass = b >> 8;                      // 0 or 1
    const int group = (idx >> 4) * 8 + (idx & 7); // 0..127, XCD co-located
    const int t01   = (idx >> 3) & 1;             // 0/1 within pass
    const int type  = pass ? (3 - t01) : t01;     // pass2 complements pass1
    const int gbase = group * 64;
    const int basin = gbase + lane;

    const int ntiles = (type + 1) * 8;            // prefix [0, 8t+8)
    const int lo1    = type * 8;                  // store tiles [8t, 8t+8)
    const int hi1    = lo1 + 8;

    // Denormalize params: sigmoid then affine to bounds.
    const float* p6  = spn + basin * 6;
    const float f    = 0.1f * sigmoidf_(p6[0]);
    const float Smax = 100.0f + 1400.0f * sigmoidf_(p6[1]);
    const float Qmax = 10.0f + 40.0f * sigmoidf_(p6[2]);
    const float Df   = 5.0f * sigmoidf_(p6[3]);
    const float Tmax = 3.0f * sigmoidf_(p6[4]);
    const float Tmin = -3.0f + 3.0f * sigmoidf_(p6[5]);

    switch (__builtin_amdgcn_readfirstlane(w)) {
        case 0:
            run<0>(prcp, temp, pet, out, lds, tid, lane, gbase, basin, ntiles,
                   lo1, hi1, f, Smax, Qmax, Df, Tmax, Tmin);
            break;
        case 1:
            run<1>(prcp, temp, pet, out, lds, tid, lane, gbase, basin, ntiles,
                   lo1, hi1, f, Smax, Qmax, Df, Tmax, Tmin);
            break;
        case 2:
            run<2>(prcp, temp, pet, out, lds, tid, lane, gbase, basin, ntiles,
                   lo1, hi1, f, Smax, Qmax, Df, Tmax, Tmin);
            break;
        default:
            run<3>(prcp, temp, pet, out, lds, tid, lane, gbase, basin, ntiles,
                   lo1, hi1, f, Smax, Qmax, Df, Tmax, Tmin);
            break;
    }
}

extern "C" void kernel_launch(void* const* d_in, const int* in_sizes, int n_in,
                              void* d_out, int out_size, void* d_ws,
                              size_t ws_size, hipStream_t stream) {
    const float* prcp = (const float*)d_in[0];
    const float* temp = (const float*)d_in[1];
    const float* pet  = (const float*)d_in[2];
    const float* spn  = (const float*)d_in[3];
    float* out        = (float*)d_out;

    hydro_kernel<<<dim3(512), dim3(256), 0, stream>>>(prcp, temp, pet, spn, out);
}